// Round 9
// baseline (1100.519 us; speedup 1.0000x reference)
//
#include <hip/hip_runtime.h>

#define B_ 32
#define N_ 8192
#define G_ 512
#define K_ 32
#define EPSF 1e-5f

typedef __attribute__((ext_vector_type(8))) short bf16x8;
typedef __attribute__((ext_vector_type(4))) float f32x4;
typedef __attribute__((ext_vector_type(2))) unsigned long long u64x2;

static __device__ __forceinline__ short f2bf(float f) {
    unsigned u = __float_as_uint(f);
    u += 0x7fffu + ((u >> 16) & 1u);  // round-to-nearest-even
    return (short)(u >> 16);
}

static __device__ __forceinline__ unsigned long long u64min(unsigned long long a,
                                                            unsigned long long b) {
    return a < b ? a : b;
}
static __device__ __forceinline__ unsigned umax32(unsigned a, unsigned b) {
    return a > b ? a : b;
}

// DPP move of a u32, 0-fill on unwritten/invalid lanes (max-neutral for
// non-negative values). CTL: 0x111..0x118 row_shr, 0x142/0x143 row_bcast15/31.
template <int CTL>
static __device__ __forceinline__ unsigned dpp_mov_u32(unsigned v) {
    return (unsigned)__builtin_amdgcn_mov_dpp((int)v, CTL, 0xf, 0xf, true);
}

// DPP move of a u64 that PRESERVES the old value on unwritten/invalid lanes
// (bound_ctrl=false, old=own value) -> safe for MIN reductions (no 0-fill).
template <int CTL>
static __device__ __forceinline__ unsigned long long dpp_upd_u64(unsigned long long k) {
    const int lo = __builtin_amdgcn_update_dpp((int)(unsigned)k, (int)(unsigned)k,
                                               CTL, 0xf, 0xf, false);
    const int hi = __builtin_amdgcn_update_dpp((int)(unsigned)(k >> 32),
                                               (int)(unsigned)(k >> 32),
                                               CTL, 0xf, 0xf, false);
    return ((unsigned long long)(unsigned)hi << 32) | (unsigned)lo;
}

// ---------------------------------------------------------------------------
// Prep: fold BN (inference) into weights/biases once.
// ---------------------------------------------------------------------------
__global__ __launch_bounds__(256) void prep_kernel(
    const float* __restrict__ w0, const float* __restrict__ b0,
    const float* __restrict__ g0, const float* __restrict__ be0,
    const float* __restrict__ m0, const float* __restrict__ v0,
    const float* __restrict__ w1, const float* __restrict__ b1,
    const float* __restrict__ g1, const float* __restrict__ be1,
    const float* __restrict__ m1, const float* __restrict__ v1,
    const float* __restrict__ w2, const float* __restrict__ b2,
    const float* __restrict__ g2, const float* __restrict__ be2,
    const float* __restrict__ m2, const float* __restrict__ v2,
    float* __restrict__ W0b, float* __restrict__ b1b, float* __restrict__ b2b,
    short* __restrict__ W1b, short* __restrict__ W2b) {
    const int t = threadIdx.x;
    if (t < 64) {
        const float sc = g0[t] / sqrtf(v0[t] + EPSF);
        W0b[t * 4 + 0] = w0[t * 3 + 0] * sc;
        W0b[t * 4 + 1] = w0[t * 3 + 1] * sc;
        W0b[t * 4 + 2] = w0[t * 3 + 2] * sc;
        W0b[t * 4 + 3] = (b0[t] - m0[t]) * sc + be0[t];
    }
    if (t < 128) b1b[t] = (b1[t] - m1[t]) * (g1[t] / sqrtf(v1[t] + EPSF)) + be1[t];
    if (t < 256) b2b[t] = (b2[t] - m2[t]) * (g2[t] / sqrtf(v2[t] + EPSF)) + be2[t];
    for (int i = t; i < 128 * 64; i += 256) {
        const int o = i >> 6;
        const float sc = g1[o] / sqrtf(v1[o] + EPSF);
        W1b[i] = f2bf(w1[i] * sc);
    }
    for (int i = t; i < 256 * 128; i += 256) {
        const int o = i >> 7;
        const float sc = g2[o] / sqrtf(v2[o] + EPSF);
        W2b[i] = f2bf(w2[i] * sc);
    }
}

// ---------------------------------------------------------------------------
// Kernel 1: FPS v7 — value/index two-phase selection.
// 512 thr, 16 pts/thread in regs. Phase A: md update + VALUE-only tree max
// + 32-bit DPP ladder + one ds_max_u32/wave. Phase B (matching threads only,
// usually 1): rescan 16 regs for smallest matching j, carry coords, 3x
// atomicMin(u64) of {(j<<9|t) key | coord}. (j,t) lex order == global idx
// order -> np.argmax first-index ties exact. No sxyz LDS array at all.
// Slots double-buffered by parity; re-init in the barrier1->barrier2 window.
// ---------------------------------------------------------------------------
__global__ __launch_bounds__(512) void fps_kernel(const float* __restrict__ pts,
                                                  float* __restrict__ centers) {
    __shared__ unsigned mslot[2];
    __shared__ unsigned long long kslot[2][3];
    __shared__ float4 c0s;

    const int b = blockIdx.x;
    const int t = threadIdx.x;
    const int l = t & 63;
    const float* p = pts + (size_t)b * (N_ * 3);

    float px[16], py[16], pz[16], md[16];
#pragma unroll
    for (int j = 0; j < 16; ++j) {
        const int idx = t + j * 512;
        px[j] = p[3 * idx + 0];
        py[j] = p[3 * idx + 1];
        pz[j] = p[3 * idx + 2];
        md[j] = 1e10f;
    }
    if (t < 2) mslot[t] = 0u;
    if (t < 6) kslot[t / 3][t % 3] = ~0ull;

    float k0x = 0.f, k0y = 0.f, k0z = 0.f, k1x = 0.f, k1y = 0.f, k1z = 0.f;
    if (t == 0) {
        float* c = centers + (size_t)b * (G_ * 3);
        c[0] = px[0]; c[1] = py[0]; c[2] = pz[0];  // center 0 = point 0
        c0s = make_float4(px[0], py[0], pz[0], 0.f);
        k0x = px[0]; k0y = py[0]; k0z = pz[0];
    }
    __syncthreads();
    float lx = c0s.x, ly = c0s.y, lz = c0s.z;

    for (int g = 1; g < G_; ++g) {
        // ---- phase A: distance update (bit-identical math) + value max ----
#pragma unroll
        for (int j = 0; j < 16; ++j) {
            const float dx = __fsub_rn(px[j], lx);
            const float dy = __fsub_rn(py[j], ly);
            const float dz = __fsub_rn(pz[j], lz);
            const float d = __fadd_rn(__fadd_rn(__fmul_rn(dx, dx), __fmul_rn(dy, dy)),
                                      __fmul_rn(dz, dz));
            md[j] = fminf(md[j], d);
        }
        float tv[16];
#pragma unroll
        for (int j = 0; j < 16; ++j) tv[j] = md[j];
#pragma unroll
        for (int s = 8; s >= 1; s >>= 1)
#pragma unroll
            for (int k = 0; k < s; ++k) tv[k] = fmaxf(tv[k], tv[k + s]);
        const unsigned vbits = __float_as_uint(tv[0]);  // dists >= 0: bits monotonic

        unsigned vv = vbits;
        vv = umax32(vv, dpp_mov_u32<0x111>(vv));
        vv = umax32(vv, dpp_mov_u32<0x112>(vv));
        vv = umax32(vv, dpp_mov_u32<0x114>(vv));
        vv = umax32(vv, dpp_mov_u32<0x118>(vv));
        vv = umax32(vv, dpp_mov_u32<0x142>(vv));  // row_bcast15
        vv = umax32(vv, dpp_mov_u32<0x143>(vv));  // row_bcast31
        if (l == 63) atomicMax(&mslot[g & 1], vv);
        __syncthreads();  // barrier 1

        const unsigned mstar = mslot[g & 1];

        // re-init the idle parity's slots (used next by iter g+1/g+2);
        // ordered after all prior readers by barrier1, before next use by barrier2
        if (t == 0) mslot[(g + 1) & 1] = 0u;
        if (t < 3) kslot[(g + 1) & 1][t] = ~0ull;

        // ---- phase B: matching threads publish {key, coord} ----
        if (vbits == mstar) {
            int jb = 15;
            float wx_ = px[15], wy_ = py[15], wz_ = pz[15];
#pragma unroll
            for (int j = 14; j >= 0; --j) {
                const bool c = (__float_as_uint(md[j]) == mstar);
                jb = c ? j : jb;
                wx_ = c ? px[j] : wx_;
                wy_ = c ? py[j] : wy_;
                wz_ = c ? pz[j] : wz_;
            }
            const unsigned long long kb =
                ((unsigned long long)(unsigned)((jb << 9) | t)) << 32;
            atomicMin(&kslot[g & 1][0], kb | (unsigned long long)__float_as_uint(wx_));
            atomicMin(&kslot[g & 1][1], kb | (unsigned long long)__float_as_uint(wy_));
            atomicMin(&kslot[g & 1][2], kb | (unsigned long long)__float_as_uint(wz_));
        }
        __syncthreads();  // barrier 2

        lx = __uint_as_float((unsigned)kslot[g & 1][0]);
        ly = __uint_as_float((unsigned)kslot[g & 1][1]);
        lz = __uint_as_float((unsigned)kslot[g & 1][2]);

        // capture center g into registers (no global store in the loop)
        const bool cap = (t == (g & 255));
        const bool hi = g >= 256;
        k0x = (cap && !hi) ? lx : k0x;
        k0y = (cap && !hi) ? ly : k0y;
        k0z = (cap && !hi) ? lz : k0z;
        k1x = (cap && hi) ? lx : k1x;
        k1y = (cap && hi) ? ly : k1y;
        k1z = (cap && hi) ? lz : k1z;
    }

    if (t < 256) {
        float* c = centers + ((size_t)b * G_ + t) * 3;
        c[0] = k0x; c[1] = k0y; c[2] = k0z;
        float* c2 = centers + ((size_t)b * G_ + 256 + t) * 3;
        c2[0] = k1x; c2[1] = k1y; c2[2] = k1z;
    }
}

// ---------------------------------------------------------------------------
// Kernel 2: kNN v2 (unchanged from R5-R8 — proven). Wave-local top-32 via DPP,
// hierarchical rescan, parallel rank-merge.
// ---------------------------------------------------------------------------
__global__ __launch_bounds__(256) void knn_kernel(const float* __restrict__ pts,
                                                  const float* __restrict__ centers,
                                                  float* __restrict__ neigh) {
    __shared__ unsigned long long wkeys[4][32];
    __shared__ int midx[32];

    const int cid = blockIdx.x;
    const int b = cid >> 9;
    const int t = threadIdx.x;
    const int w = t >> 6;
    const int l = t & 63;
    const float* p = pts + (size_t)b * (N_ * 3);
    const float* c = centers + (size_t)cid * 3;
    const float cx = c[0], cy = c[1], cz = c[2];

    const int iy0 = (w << 11) + l;

    unsigned int db[32];
#pragma unroll
    for (int i = 0; i < 32; ++i) {
        const int idx = iy0 + (i << 6);
        const float dx = __fsub_rn(p[3 * idx + 0], cx);
        const float dy = __fsub_rn(p[3 * idx + 1], cy);
        const float dz = __fsub_rn(p[3 * idx + 2], cz);
        const float d = __fadd_rn(__fadd_rn(__fmul_rn(dx, dx), __fmul_rn(dy, dy)),
                                  __fmul_rn(dz, dz));
        db[i] = __float_as_uint(d);
    }

    unsigned int excl = 0u;
    unsigned long long gm0, gm1, gm2, gm3;

#define KNN_SCAN_GROUP(G, DEST)                                               \
    {                                                                         \
        unsigned long long nm = ~0ull;                                        \
        _Pragma("unroll") for (int j = 0; j < 8; ++j) {                       \
            const int i = ((G) << 3) + j;                                     \
            if (!(excl & (1u << i))) {                                        \
                const unsigned long long k2 =                                 \
                    ((unsigned long long)db[i] << 13) |                       \
                    (unsigned long long)(unsigned)(iy0 + (i << 6));           \
                nm = (nm < k2) ? nm : k2;                                     \
            }                                                                 \
        }                                                                     \
        DEST = nm;                                                            \
    }

    KNN_SCAN_GROUP(0, gm0)
    KNN_SCAN_GROUP(1, gm1)
    KNN_SCAN_GROUP(2, gm2)
    KNN_SCAN_GROUP(3, gm3)
    unsigned long long lkey = u64min(u64min(gm0, gm1), u64min(gm2, gm3));

    for (int r = 0; r < K_; ++r) {
        unsigned long long x = lkey;
        x = u64min(x, dpp_upd_u64<0x111>(x));
        x = u64min(x, dpp_upd_u64<0x112>(x));
        x = u64min(x, dpp_upd_u64<0x114>(x));
        x = u64min(x, dpp_upd_u64<0x118>(x));
        x = u64min(x, dpp_upd_u64<0x142>(x));  // row_bcast15
        x = u64min(x, dpp_upd_u64<0x143>(x));  // row_bcast31
        const unsigned blo = (unsigned)__builtin_amdgcn_readlane((int)(unsigned)x, 63);
        const unsigned bhi =
            (unsigned)__builtin_amdgcn_readlane((int)(unsigned)(x >> 32), 63);
        const unsigned long long best = ((unsigned long long)bhi << 32) | blo;

        if (best == lkey) {
            const int i = ((int)(best & 0x1FFFull) >> 6) & 31;
            excl |= 1u << i;
            switch (i >> 3) {
                case 0: KNN_SCAN_GROUP(0, gm0) break;
                case 1: KNN_SCAN_GROUP(1, gm1) break;
                case 2: KNN_SCAN_GROUP(2, gm2) break;
                default: KNN_SCAN_GROUP(3, gm3) break;
            }
            lkey = u64min(u64min(gm0, gm1), u64min(gm2, gm3));
        }
        if (l == 0) wkeys[w][r] = best;
    }
#undef KNN_SCAN_GROUP
    __syncthreads();

    if (t < 128) {
        const int wv = t >> 5;
        const int pos = t & 31;
        const unsigned long long mykey = wkeys[wv][pos];
        int rank = pos;
#pragma unroll
        for (int d = 1; d < 4; ++d) {
            const int ol = (wv + d) & 3;
            int cnt = 0;
#pragma unroll
            for (int s = 32; s >= 1; s >>= 1) {
                const int n = cnt + s;
                if (n <= 32 && wkeys[ol][n - 1] < mykey) cnt = n;
            }
            rank += cnt;
        }
        if (rank < 32) midx[rank] = (int)(mykey & 0x1FFFull);
    }
    __syncthreads();

    if (t < 32) {
        const int idx = midx[t];
        float* o3 = neigh + (((size_t)cid * K_) + t) * 3;
        o3[0] = __fsub_rn(p[3 * idx + 0], cx);
        o3[1] = __fsub_rn(p[3 * idx + 1], cy);
        o3[2] = __fsub_rn(p[3 * idx + 2], cz);
    }
}

// ---------------------------------------------------------------------------
// Kernel 3: MFMA MLP (unchanged from R4-R8). 512 thr x 256 points/block.
// ---------------------------------------------------------------------------
__global__ __launch_bounds__(512) void mlp_kernel(
    const float* __restrict__ neigh, const float* __restrict__ W0b,
    const float* __restrict__ b1b, const float* __restrict__ b2b,
    const short* __restrict__ W1b, const short* __restrict__ W2b,
    float* __restrict__ out) {
    __shared__ bf16x8 lw1v[1024];
    __shared__ bf16x8 lw2v[4096];
    __shared__ bf16x8 lh2v[8 * 512];
    __shared__ float lw0[256];
    __shared__ float lb1[128];
    __shared__ float lb2[256];
    __shared__ float colmax[256];

    const int t = threadIdx.x;
    const int w = t >> 6;
    const int l = t & 63;
    const int lr = l & 15;
    const int lg = l >> 4;

    {
        char* d1 = (char*)lw1v;
        for (int i = t; i < 1024; i += 512) {
            const int d = i * 16;
            const int src = d ^ ((((unsigned)d >> 7) & 7) << 4);
            *(bf16x8*)(d1 + d) = *(const bf16x8*)((const char*)W1b + src);
        }
        char* d2 = (char*)lw2v;
        for (int i = t; i < 4096; i += 512) {
            const int d = i * 16;
            const int src = d ^ ((((unsigned)d >> 8) & 7) << 4);
            *(bf16x8*)(d2 + d) = *(const bf16x8*)((const char*)W2b + src);
        }
        if (t < 256) lw0[t] = W0b[t];
        if (t < 128) lb1[t] = b1b[t];
        if (t < 256) lb2[t] = b2b[t];
        if (t < 256) colmax[t] = 0.0f;
    }
    __syncthreads();

    const size_t pbase = (size_t)blockIdx.x * 256 + w * 32;
    bf16x8 a1[2][2];
#pragma unroll
    for (int m = 0; m < 2; ++m) {
        const float* pp = neigh + (pbase + m * 16 + lr) * 3;
        const float x0 = pp[0], x1 = pp[1], x2 = pp[2];
#pragma unroll
        for (int s = 0; s < 2; ++s) {
            bf16x8 v;
#pragma unroll
            for (int j = 0; j < 8; ++j) {
                const int c = s * 32 + lg * 8 + j;
                const float4 wv = *(const float4*)&lw0[c * 4];
                float val = fmaf(x2, wv.z, fmaf(x1, wv.y, x0 * wv.x)) + wv.w;
                v[j] = f2bf(fmaxf(val, 0.0f));
            }
            a1[m][s] = v;
        }
    }

    const f32x4 vzero = {0.f, 0.f, 0.f, 0.f};
    f32x4 acc2[2][8];
#pragma unroll
    for (int m = 0; m < 2; ++m)
#pragma unroll
        for (int n = 0; n < 8; ++n) acc2[m][n] = vzero;

    const char* w1p = (const char*)lw1v;
#pragma unroll
    for (int s = 0; s < 2; ++s) {
#pragma unroll
        for (int n = 0; n < 8; ++n) {
            const int o = n * 16 + lr;
            int byte = o * 128 + s * 64 + lg * 16;
            byte ^= ((o & 7) << 4);
            const bf16x8 bfr = *(const bf16x8*)(w1p + byte);
            acc2[0][n] = __builtin_amdgcn_mfma_f32_16x16x32_bf16(a1[0][s], bfr, acc2[0][n], 0, 0, 0);
            acc2[1][n] = __builtin_amdgcn_mfma_f32_16x16x32_bf16(a1[1][s], bfr, acc2[1][n], 0, 0, 0);
        }
    }

    char* myh2 = (char*)(lh2v + w * 512);
#pragma unroll
    for (int m = 0; m < 2; ++m)
#pragma unroll
        for (int n = 0; n < 8; ++n) {
            const int o = n * 16 + lr;
            const float bb = lb1[o];
#pragma unroll
            for (int q = 0; q < 4; ++q) {
                const int row = m * 16 + lg * 4 + q;
                int byte = row * 256 + o * 2;
                byte ^= ((row & 7) << 4);
                *(short*)(myh2 + byte) = f2bf(fmaxf(acc2[m][n][q] + bb, 0.0f));
            }
        }

    f32x4 acc3[2][16];
#pragma unroll
    for (int m = 0; m < 2; ++m)
#pragma unroll
        for (int n = 0; n < 16; ++n) acc3[m][n] = vzero;

    const char* w2p = (const char*)lw2v;
#pragma unroll
    for (int s = 0; s < 4; ++s) {
        bf16x8 a[2];
#pragma unroll
        for (int m = 0; m < 2; ++m) {
            const int row = m * 16 + lr;
            int byte = row * 256 + s * 64 + lg * 16;
            byte ^= ((row & 7) << 4);
            a[m] = *(const bf16x8*)(myh2 + byte);
        }
#pragma unroll
        for (int n = 0; n < 16; ++n) {
            const int o = n * 16 + lr;
            int byte = o * 256 + s * 64 + lg * 16;
            byte ^= ((o & 7) << 4);
            const bf16x8 bfr = *(const bf16x8*)(w2p + byte);
            acc3[0][n] = __builtin_amdgcn_mfma_f32_16x16x32_bf16(a[0], bfr, acc3[0][n], 0, 0, 0);
            acc3[1][n] = __builtin_amdgcn_mfma_f32_16x16x32_bf16(a[1], bfr, acc3[1][n], 0, 0, 0);
        }
    }

#pragma unroll
    for (int n = 0; n < 16; ++n) {
        const int o = n * 16 + lr;
        const float bb = lb2[o];
        float mx = 0.0f;
#pragma unroll
        for (int m = 0; m < 2; ++m)
#pragma unroll
            for (int q = 0; q < 4; ++q) mx = fmaxf(mx, acc3[m][n][q] + bb);
        mx = fmaxf(mx, 0.0f);
        mx = fmaxf(mx, __shfl_xor(mx, 16, 64));
        mx = fmaxf(mx, __shfl_xor(mx, 32, 64));
        if (lg == 0) atomicMax((unsigned int*)&colmax[o], __float_as_uint(mx));
    }
    __syncthreads();
    if (t < 256) {
        const int b = (int)(blockIdx.x >> 6);
        atomicMax((unsigned int*)out + b * 256 + t, __float_as_uint(colmax[t]));
    }
}

// ---------------------------------------------------------------------------
extern "C" void kernel_launch(void* const* d_in, const int* in_sizes, int n_in,
                              void* d_out, int out_size, void* d_ws, size_t ws_size,
                              hipStream_t stream) {
    const float* pts = (const float*)d_in[0];
    const float* w0 = (const float*)d_in[1];
    const float* b0 = (const float*)d_in[2];
    const float* g0 = (const float*)d_in[3];
    const float* be0 = (const float*)d_in[4];
    const float* m0 = (const float*)d_in[5];
    const float* v0 = (const float*)d_in[6];
    const float* w1 = (const float*)d_in[7];
    const float* b1 = (const float*)d_in[8];
    const float* g1 = (const float*)d_in[9];
    const float* be1 = (const float*)d_in[10];
    const float* m1 = (const float*)d_in[11];
    const float* v1 = (const float*)d_in[12];
    const float* w2 = (const float*)d_in[13];
    const float* b2 = (const float*)d_in[14];
    const float* g2 = (const float*)d_in[15];
    const float* be2 = (const float*)d_in[16];
    const float* m2 = (const float*)d_in[17];
    const float* v2 = (const float*)d_in[18];

    char* ws = (char*)d_ws;
    float* centers = (float*)ws;                        // 192KB @ 0
    float* neigh = (float*)(ws + (size_t)262144);       // 6.29MB
    char* wb = ws + (size_t)6553600;                    // weights region
    float* W0b = (float*)(wb + 0);                      // 1KB
    float* b1b = (float*)(wb + 1024);                   // 512B
    float* b2b = (float*)(wb + 1536);                   // 1KB
    short* W1b = (short*)(wb + 2560);                   // 16KB
    short* W2b = (short*)(wb + 2560 + 16384);           // 64KB

    hipMemsetAsync(d_out, 0, (size_t)out_size * sizeof(float), stream);
    prep_kernel<<<1, 256, 0, stream>>>(w0, b0, g0, be0, m0, v0,
                                       w1, b1, g1, be1, m1, v1,
                                       w2, b2, g2, be2, m2, v2,
                                       W0b, b1b, b2b, W1b, W2b);
    fps_kernel<<<B_, 512, 0, stream>>>(pts, centers);
    knn_kernel<<<B_ * G_, 256, 0, stream>>>(pts, centers, neigh);
    mlp_kernel<<<(B_ * G_ * K_) / 256, 512, 0, stream>>>(
        neigh, W0b, b1b, b2b, W1b, W2b, (float*)d_out);
}